// Round 7
// baseline (361.046 us; speedup 1.0000x reference)
//
#include <hip/hip_runtime.h>
#include <hip/hip_bf16.h>

typedef short short8 __attribute__((ext_vector_type(8)));
typedef float f32x4 __attribute__((ext_vector_type(4)));

#define BM 128
#define BN 128

typedef const __attribute__((address_space(1))) void gas_t;
typedef __attribute__((address_space(3))) void las_t;

__device__ __forceinline__ unsigned short f2bf(float f) {
  unsigned int u = __float_as_uint(f);
  u += 0x7FFFu + ((u >> 16) & 1u);   // round-to-nearest-even
  return (unsigned short)(u >> 16);
}

// tanh via single v_exp_f32 + v_rcp_f32: tanh(x) = 1 - 2/(e^2x + 1).
__device__ __forceinline__ float fast_tanh(float x) {
  x = fminf(fmaxf(x, -10.f), 10.f);
  float t = __builtin_amdgcn_exp2f(x * 2.8853900817779268f);  // 2*log2(e)
  return 1.f - 2.f * __builtin_amdgcn_rcpf(t + 1.f);
}

struct GemmP {
  const unsigned short* A;
  const unsigned short* A2;    // second A source for k >= kSplit (piecewise concat rows)
  const unsigned short* Bm;
  void* C;
  // alt pointer set for merged launches: used when z >= zSplit (z' = z - zSplit)
  const unsigned short* A_b;
  const unsigned short* A2_b;
  const unsigned short* Bm_b;
  void* C_b;
  const float* mask_p;
  const float* mask_s;
  const float* bias;
  const float* bias_b;
  long long sAb, sAh, sBb, sBh, sCb, sCh;  // batch strides (shared by both halves)
  int lda, lda2, ldb, ldc, M, N, K, Hh, kSplit, zSplit;  // kSplit=0/zSplit=0 -> disabled
};

// TA: 0 = A is M x K row-major (global_load_lds direct staging, LDS pitch 32, no pad)
//     1 = A stored K x M row-major (VALU transpose staging, LDS pitch 40 padded)
// B is always N x K row-major (direct lds-DMA staging).
// EPI: 0 = store bf16; 1 = tanh*mask store bf16; 2 = relu + atomic max into f32 pool; 3 = +bias, relu, store f32
// K-loop: BK=64 as two BK=32 half-tiles; all staging pointers strength-reduced
// (precomputed before the loop, advanced by constant increments per iteration).
template <int TA, int EPI>
__global__ __launch_bounds__(256) void gemm_k(GemmP p) {
  constexpr int PA = (TA == 0) ? 32 : 40;
  constexpr int HSA = (TA == 0) ? 4096 : 5120;  // shorts per A half-tile
  __shared__ __align__(16) unsigned short As[2 * HSA];
  __shared__ __align__(16) unsigned short Bs[8192];

  int z = blockIdx.z;
  const unsigned short* Abase = p.A;
  const unsigned short* A2 = p.A2;
  const unsigned short* Bbase = p.Bm;
  void* Cvp = p.C;
  const float* bias = p.bias;
  if (p.zSplit && z >= p.zSplit) {
    z -= p.zSplit;
    Abase = p.A_b; A2 = p.A2_b; Bbase = p.Bm_b; Cvp = p.C_b; bias = p.bias_b;
  }
  const int zb = z / p.Hh, zh = z % p.Hh;
  const unsigned short* A = Abase + (size_t)zb * p.sAb + (size_t)zh * p.sAh;
  const unsigned short* B = Bbase + (size_t)zb * p.sBb + (size_t)zh * p.sBh;
  const int m0 = blockIdx.x * BM, n0 = blockIdx.y * BN;
  const int tid = threadIdx.x;
  const int wid = tid >> 6, lane = tid & 63;
  const int wm = (wid >> 1) * 64, wn = (wid & 1) * 64;
  const int lrow = lane & 15, lkg = lane >> 4;

  f32x4 acc[4][4] = {};

  // direct-staging lane mapping: LDS byte (q*4096 + tid*16) -> row = q*64 + tid/4, k-group = tid&3
  const int dm = tid >> 2, dkg = tid & 3;

  // ---- strength-reduced staging pointers ----
  const unsigned short* bP[4];  // [h*2+q], advance +64 elems/iter
#pragma unroll
  for (int h = 0; h < 2; ++h)
#pragma unroll
    for (int q = 0; q < 2; ++q)
      bP[h * 2 + q] = B + (size_t)(n0 + q * 64 + dm) * p.ldb + (h * 32 + dkg * 8);

  const unsigned short* aP[4];
  if (TA == 0) {
#pragma unroll
    for (int h = 0; h < 2; ++h)
#pragma unroll
      for (int q = 0; q < 2; ++q)
        aP[h * 2 + q] = A + (size_t)(m0 + q * 64 + dm) * p.lda + (h * 32 + dkg * 8);
  } else {
    const int kk = tid & 31, mg = (tid >> 5) << 4;
    aP[0] = A + (size_t)kk * p.lda + (m0 + mg);
    aP[1] = A + (size_t)(32 + kk) * p.lda + (m0 + mg);
    aP[2] = aP[3] = aP[0];
  }

  auto kstep = [&]() {
    if (TA == 0) {
#pragma unroll
      for (int j = 0; j < 4; ++j) {
        __builtin_amdgcn_global_load_lds((gas_t*)aP[j],
                                         (las_t*)&As[(j >> 1) * 4096 + (j & 1) * 2048 + wid * 512],
                                         16, 0, 0);
        aP[j] += 64;
      }
    } else {
      const int kk = tid & 31, mg = (tid >> 5) << 4;
#pragma unroll
      for (int h = 0; h < 2; ++h) {
        const unsigned short* src = aP[h];
        uint4 v0 = *(const uint4*)src;
        uint4 v1 = *(const uint4*)(src + 8);
        aP[h] += (size_t)64 * p.lda;
        unsigned short tmp[16];
        *(uint4*)&tmp[0] = v0;
        *(uint4*)&tmp[8] = v1;
#pragma unroll
        for (int j = 0; j < 16; ++j) As[h * HSA + (mg + j) * PA + kk] = tmp[j];
      }
    }
#pragma unroll
    for (int j = 0; j < 4; ++j) {
      __builtin_amdgcn_global_load_lds((gas_t*)bP[j],
                                       (las_t*)&Bs[(j >> 1) * 4096 + (j & 1) * 2048 + wid * 512],
                                       16, 0, 0);
      bP[j] += 64;
    }
    __syncthreads();

#pragma unroll
    for (int h = 0; h < 2; ++h) {
      short8 af[4], bfv[4];
#pragma unroll
      for (int mt = 0; mt < 4; ++mt)
        af[mt] = *(const short8*)&As[h * HSA + (wm + mt * 16 + lrow) * PA + lkg * 8];
#pragma unroll
      for (int nt = 0; nt < 4; ++nt)
        bfv[nt] = *(const short8*)&Bs[h * 4096 + (wn + nt * 16 + lrow) * 32 + lkg * 8];
#pragma unroll
      for (int mt = 0; mt < 4; ++mt)
#pragma unroll
        for (int nt = 0; nt < 4; ++nt)
          acc[mt][nt] = __builtin_amdgcn_mfma_f32_16x16x32_bf16(af[mt], bfv[nt], acc[mt][nt], 0, 0, 0);
    }
    __syncthreads();
  };

  const int nIter = p.K >> 6;
  const int nIter1 = p.kSplit ? (p.kSplit >> 6) : nIter;
  for (int it = 0; it < nIter1; ++it) kstep();
  if (TA == 0 && p.kSplit) {
#pragma unroll
    for (int h = 0; h < 2; ++h)
#pragma unroll
      for (int q = 0; q < 2; ++q)
        aP[h * 2 + q] = A2 + (size_t)(m0 + q * 64 + dm) * p.lda2 + (h * 32 + dkg * 8);
    for (int it = nIter1; it < nIter; ++it) kstep();
  }

  unsigned short* Cu = (unsigned short*)Cvp + (size_t)zb * p.sCb + (size_t)zh * p.sCh;
  float* Cf = (float*)Cvp + (size_t)zb * p.sCb + (size_t)zh * p.sCh;

  // precomputed epilogue offsets: 16 row offsets, 4 col offsets
  size_t rOff[16];
  int cOff[4];
#pragma unroll
  for (int mt = 0; mt < 4; ++mt)
#pragma unroll
    for (int r = 0; r < 4; ++r)
      rOff[mt * 4 + r] = (size_t)(m0 + wm + mt * 16 + lkg * 4 + r) * p.ldc;
#pragma unroll
  for (int nt = 0; nt < 4; ++nt)
    cOff[nt] = n0 + wn + nt * 16 + lrow;

  // hoisted epilogue operands (16 row values, 4 col values)
  float mp[16], ms[4];
  if constexpr (EPI == 1) {
#pragma unroll
    for (int mt = 0; mt < 4; ++mt)
#pragma unroll
      for (int r = 0; r < 4; ++r)
        mp[mt * 4 + r] = p.mask_p[(size_t)zb * p.M + (m0 + wm + mt * 16 + lkg * 4 + r)];
#pragma unroll
    for (int nt = 0; nt < 4; ++nt)
      ms[nt] = p.mask_s[(size_t)zb * p.N + cOff[nt]];
  }
  if constexpr (EPI == 3) {
#pragma unroll
    for (int nt = 0; nt < 4; ++nt)
      ms[nt] = bias[cOff[nt]];
  }

#pragma unroll
  for (int mt = 0; mt < 4; ++mt) {
#pragma unroll
    for (int nt = 0; nt < 4; ++nt) {
      f32x4 a = acc[mt][nt];
#pragma unroll
      for (int r = 0; r < 4; ++r) {
        const size_t idx = rOff[mt * 4 + r] + cOff[nt];
        const float v = a[r];
        if constexpr (EPI == 0) {
          Cu[idx] = f2bf(v);
        } else if constexpr (EPI == 1) {
          Cu[idx] = f2bf(fast_tanh(v) * (mp[mt * 4 + r] * ms[nt]));
        } else if constexpr (EPI == 2) {
          // relu output >= 0, pool initialized to 0 -> int compare == float compare
          atomicMax((int*)Cf + idx, __float_as_int(fmaxf(v, 0.f)));
        } else {
          Cf[idx] = fmaxf(v + ms[nt], 0.f);
        }
      }
    }
  }
}

// two tensors fp32->bf16 in one launch (i < n4 -> a, else -> b)
__global__ void cvt2_bf16_v4(const float4* a, const float4* b, ushort4* oa, ushort4* ob, int n4) {
  int i = blockIdx.x * 256 + threadIdx.x;
  const float4* s;
  ushort4* d;
  int j;
  if (i < n4) { s = a; d = oa; j = i; }
  else { j = i - n4; if (j >= n4) return; s = b; d = ob; }
  float4 v = s[j];
  ushort4 o;
  o.x = f2bf(v.x); o.y = f2bf(v.y); o.z = f2bf(v.z); o.w = f2bf(v.w);
  d[j] = o;
}

__global__ void cvt_bf16_v4(const float4* in, ushort4* out, int n4) {
  int i = blockIdx.x * 256 + threadIdx.x;
  if (i >= n4) return;
  float4 v = in[i];
  ushort4 o;
  o.x = f2bf(v.x); o.y = f2bf(v.y); o.z = f2bf(v.z); o.w = f2bf(v.w);
  out[i] = o;
}

// out[z][c][r] = in[z][r][c]  (fp32 -> bf16, LDS-tiled transpose, 32x32 tiles)
// optional second tensor pair for z >= zSplit
__global__ __launch_bounds__(256) void trans_bf16(const float* in, unsigned short* out,
                                                  const float* in2, unsigned short* out2,
                                                  int R, int C, int zSplit) {
  __shared__ float tile[32][33];
  int z = blockIdx.z;
  const float* ib = in;
  unsigned short* ob = out;
  if (zSplit && z >= zSplit) { z -= zSplit; ib = in2; ob = out2; }
  const int r0 = blockIdx.y * 32, c0 = blockIdx.x * 32;
  const int tx = threadIdx.x & 31, ty = threadIdx.x >> 5;  // 32 x 8
  const float* src = ib + (size_t)z * R * C;
  unsigned short* dst = ob + (size_t)z * R * C;
#pragma unroll
  for (int j = 0; j < 4; ++j)
    tile[ty + j * 8][tx] = src[(size_t)(r0 + ty + j * 8) * C + (c0 + tx)];
  __syncthreads();
#pragma unroll
  for (int j = 0; j < 4; ++j)
    dst[(size_t)(c0 + ty + j * 8) * R + (r0 + tx)] = f2bf(tile[tx][ty + j * 8]);
}

template <int TA, int EPI>
static inline void run_gemm(const GemmP& q, int Z, hipStream_t stream) {
  dim3 grid(q.M / BM, q.N / BN, Z);
  gemm_k<TA, EPI><<<grid, dim3(256), 0, stream>>>(q);
}

extern "C" void kernel_launch(void* const* d_in, const int* in_sizes, int n_in,
                              void* d_out, int out_size, void* d_ws, size_t ws_size,
                              hipStream_t stream) {
  (void)in_sizes; (void)n_in; (void)out_size; (void)ws_size;
  const float* primary   = (const float*)d_in[0];
  const float* secondary = (const float*)d_in[1];
  const float* pmask     = (const float*)d_in[2];
  const float* smask     = (const float*)d_in[3];
  const float* W_aff     = (const float*)d_in[4];
  const float* W_p       = (const float*)d_in[5];
  const float* W_s       = (const float*)d_in[6];
  const float* W_fp      = (const float*)d_in[7];
  const float* b_fp      = (const float*)d_in[8];
  const float* W_fs      = (const float*)d_in[9];
  const float* b_fs      = (const float*)d_in[10];

  constexpr int Bb = 16, L = 512, Dd = 512, Hh = 8, HDd = 128, INNER = 1024, CAT = 640;
  constexpr int NT = Hh * Dd;                      // 4096: stacked W_aff heads
  constexpr long long LD = (long long)L * Dd;      // 262144
  constexpr long long LL = (long long)L * L;       // 262144

  char* base = (char*)d_ws;
  size_t off = 0;
  auto alloc = [&](size_t bytes) -> void* {
    void* r = base + off;
    off += (bytes + 255) & ~(size_t)255;
    return r;
  };

  unsigned short* Pbf   = (unsigned short*)alloc((size_t)Bb * L * Dd * 2);
  unsigned short* Sbf   = (unsigned short*)alloc((size_t)Bb * L * Dd * 2);
  unsigned short* WaT   = (unsigned short*)alloc((size_t)NT * Dd * 2);        // [h*512+f][e]
  unsigned short* WpT   = (unsigned short*)alloc((size_t)INNER * Dd * 2);     // [n][e]
  unsigned short* WsT   = (unsigned short*)alloc((size_t)INNER * Dd * 2);
  unsigned short* WfpT  = (unsigned short*)alloc((size_t)Dd * CAT * 2);       // [n][k]
  unsigned short* WfsT  = (unsigned short*)alloc((size_t)Dd * CAT * 2);
  unsigned short* psT   = (unsigned short*)alloc((size_t)Bb * INNER * L * 2); // [b][d(1024)][j]
  unsigned short* ppT   = (unsigned short*)alloc((size_t)Bb * INNER * L * 2); // [b][d(1024)][i]
  unsigned short* Tbuf  = (unsigned short*)alloc((size_t)Bb * L * NT * 2);    // [b*L+i][h*512+f]
  unsigned short* affb  = (unsigned short*)alloc((size_t)Bb * Hh * L * L * 2);
  float* pool_p = (float*)alloc((size_t)Bb * L * HDd * 4);                    // adjacent with pool_s
  float* pool_s = (float*)alloc((size_t)Bb * L * HDd * 4);
  unsigned short* poolPbf = (unsigned short*)alloc((size_t)Bb * L * HDd * 2); // adjacent with poolSbf
  unsigned short* poolSbf = (unsigned short*)alloc((size_t)Bb * L * HDd * 2);

  // ---- convert inputs (one launch), transpose weights to N x K (3 launches) ----
  {
    const int n4 = (Bb * L * Dd) / 4;
    cvt2_bf16_v4<<<dim3((2 * n4) / 256), dim3(256), 0, stream>>>(
        (const float4*)primary, (const float4*)secondary, (ushort4*)Pbf, (ushort4*)Sbf, n4);
  }
  trans_bf16<<<dim3(Dd / 32, Dd / 32, Hh), dim3(256), 0, stream>>>(
      W_aff, WaT, nullptr, nullptr, Dd, Dd, 0);
  trans_bf16<<<dim3(INNER / 32, Dd / 32, 2), dim3(256), 0, stream>>>(
      W_p, WpT, W_s, WsT, Dd, INNER, 1);
  trans_bf16<<<dim3(Dd / 32, CAT / 32, 2), dim3(256), 0, stream>>>(
      W_fp, WfpT, W_fs, WfsT, CAT, Dd, 1);

  hipMemsetAsync(pool_p, 0, (size_t)2 * Bb * L * HDd * 4, stream);  // pool_p + pool_s (adjacent)

  // ---- Tbuf = P @ [Waff_0..Waff_7]  (M=8192, N=4096, K=512) ----
  {
    GemmP g{};
    g.A = Pbf; g.lda = Dd;
    g.Bm = WaT; g.ldb = Dd;
    g.C = Tbuf; g.ldc = NT;
    g.M = Bb * L; g.N = NT; g.K = Dd; g.Hh = 1;
    run_gemm<0, 0>(g, 1, stream);
  }

  // ---- merged: psT[b] = (S_b @ W_s)^T (z<16) and ppT[b] = (P_b @ W_p)^T (z>=16) ----
  {
    GemmP g{};
    g.A = WsT; g.lda = Dd; g.sAb = 0;
    g.Bm = Sbf; g.ldb = Dd; g.sBb = LD;
    g.C = psT; g.ldc = L; g.sCb = (long long)INNER * L;
    g.A_b = WpT; g.Bm_b = Pbf; g.C_b = ppT;
    g.M = INNER; g.N = L; g.K = Dd; g.Hh = 1; g.zSplit = Bb;
    run_gemm<0, 0>(g, 2 * Bb, stream);
  }

  // ---- aff[b,h] = tanh(T[b,h] @ S_b^T) * mask ; T lives in Tbuf cols h*512.. ----
  {
    GemmP g{};
    g.A = Tbuf; g.lda = NT; g.sAb = (long long)L * NT; g.sAh = Dd;
    g.Bm = Sbf; g.ldb = Dd; g.sBb = LD; g.sBh = 0;
    g.C = affb; g.ldc = L; g.sCb = (long long)Hh * LL; g.sCh = LL;
    g.mask_p = pmask; g.mask_s = smask;
    g.M = L; g.N = L; g.K = Dd; g.Hh = Hh;
    run_gemm<0, 1>(g, Bb * Hh, stream);
  }

  // ---- pool_s max= relu(aff[b,h] @ psT[b][h*128..]^T) : A fast (M x K = i x j) ----
  {
    GemmP g{};
    g.A = affb; g.lda = L; g.sAb = (long long)Hh * LL; g.sAh = LL;
    g.Bm = psT; g.ldb = L; g.sBb = (long long)INNER * L; g.sBh = (long long)HDd * L;
    g.C = pool_s; g.ldc = HDd; g.sCb = (long long)L * HDd; g.sCh = 0;
    g.M = L; g.N = HDd; g.K = L; g.Hh = Hh;
    run_gemm<0, 2>(g, Bb * Hh, stream);
  }

  // ---- pool_p max= relu(aff[b,h]^T @ ppT[b][h*128..]^T) : A = affb read as K x M (TA=1) ----
  {
    GemmP g{};
    g.A = affb; g.lda = L; g.sAb = (long long)Hh * LL; g.sAh = LL;  // stored[k=i][m=j]
    g.Bm = ppT; g.ldb = L; g.sBb = (long long)INNER * L; g.sBh = (long long)HDd * L;
    g.C = pool_p; g.ldc = HDd; g.sCb = (long long)L * HDd; g.sCh = 0;
    g.M = L; g.N = HDd; g.K = L; g.Hh = Hh;
    run_gemm<1, 2>(g, Bb * Hh, stream);
  }

  // ---- pools -> bf16 (pool_p,pool_s adjacent -> poolPbf,poolSbf adjacent; one launch) ----
  {
    const int n4 = (2 * Bb * L * HDd) / 4;
    cvt_bf16_v4<<<dim3((n4 + 255) / 256), dim3(256), 0, stream>>>((const float4*)pool_p, (ushort4*)poolPbf, n4);
  }

  // ---- merged output FFNs: z=0 -> out_p, z=1 -> out_s; A = [X | pool] piecewise at k=512 ----
  {
    GemmP g{};
    g.A = Pbf; g.lda = Dd;
    g.A2 = poolSbf; g.lda2 = HDd; g.kSplit = Dd;
    g.Bm = WfpT; g.ldb = CAT;
    g.C = d_out; g.ldc = Dd;
    g.bias = b_fp;
    g.A_b = Sbf; g.A2_b = poolPbf; g.Bm_b = WfsT;
    g.C_b = (float*)d_out + (size_t)Bb * L * Dd;
    g.bias_b = b_fs;
    g.M = Bb * L; g.N = Dd; g.K = CAT; g.Hh = 1; g.zSplit = 1;
    run_gemm<0, 3>(g, 2, stream);
  }
}

// Round 8
// 344.850 us; speedup vs baseline: 1.0470x; 1.0470x over previous
//
#include <hip/hip_runtime.h>
#include <hip/hip_bf16.h>

typedef short short8 __attribute__((ext_vector_type(8)));
typedef float f32x4 __attribute__((ext_vector_type(4)));

#define BM 128
#define BN 128

typedef const __attribute__((address_space(1))) void gas_t;
typedef __attribute__((address_space(3))) void las_t;

__device__ __forceinline__ unsigned short f2bf(float f) {
  unsigned int u = __float_as_uint(f);
  u += 0x7FFFu + ((u >> 16) & 1u);   // round-to-nearest-even
  return (unsigned short)(u >> 16);
}

// tanh via single v_exp_f32 + v_rcp_f32: tanh(x) = 1 - 2/(e^2x + 1).
__device__ __forceinline__ float fast_tanh(float x) {
  x = fminf(fmaxf(x, -10.f), 10.f);
  float t = __builtin_amdgcn_exp2f(x * 2.8853900817779268f);  // 2*log2(e)
  return 1.f - 2.f * __builtin_amdgcn_rcpf(t + 1.f);
}

struct GemmP {
  const unsigned short* A;
  const unsigned short* Bm;
  void* C;
  const float* A2f;            // f32 second A source for k >= kSplit (converted during staging)
  // alt pointer set for merged launches: used when z >= zSplit
  const unsigned short* A_b;
  const unsigned short* Bm_b;
  void* C_b;
  const float* A2f_b;
  const float* mask_p;
  const float* mask_s;
  const float* bias;
  const float* bias_b;
  long long sAb, sAh, sBb, sBh, sCb, sCh;
  int lda, lda2, ldb, ldc, M, N, K, Hh, kSplit, zSplit, nbx, nby;
};

// TA: 0 = A is M x K row-major (lds-DMA staging, pitch 32); 1 = A stored K x M (VALU transpose staging, pitch 40).
// B always N x K row-major (lds-DMA).
// EPI: 0 bf16 store; 1 tanh*mask bf16; 2 relu+atomicMax f32 pool; 3 +bias,relu f32.
// K-loop: BK=64 as two BK=32 half-tiles; kSplit handled as a separate second phase
// staging f32 A2 with in-register convert (reproduces the lds-DMA layout exactly).
template <int TA, int EPI>
__device__ __forceinline__ void gemm_body(const GemmP& p, int bx, int by, int bz, char* smem_) {
  constexpr int PA = (TA == 0) ? 32 : 40;
  constexpr int HSA = (TA == 0) ? 4096 : 5120;  // shorts per A half-tile
  unsigned short* As = (unsigned short*)smem_;
  unsigned short* Bs = (unsigned short*)(smem_ + 2 * HSA * 2);

  int z = bz;
  const unsigned short* Abase = p.A;
  const unsigned short* Bbase = p.Bm;
  void* Cvp = p.C;
  const float* A2f = p.A2f;
  const float* bias = p.bias;
  if (p.zSplit && z >= p.zSplit) {
    z -= p.zSplit;
    Abase = p.A_b; Bbase = p.Bm_b; Cvp = p.C_b; A2f = p.A2f_b; bias = p.bias_b;
  }
  const int zb = z / p.Hh, zh = z % p.Hh;
  const unsigned short* A = Abase + (size_t)zb * p.sAb + (size_t)zh * p.sAh;
  const unsigned short* B = Bbase + (size_t)zb * p.sBb + (size_t)zh * p.sBh;
  const int m0 = bx * BM, n0 = by * BN;
  const int tid = threadIdx.x;
  const int wid = tid >> 6, lane = tid & 63;
  const int wm = (wid >> 1) * 64, wn = (wid & 1) * 64;
  const int lrow = lane & 15, lkg = lane >> 4;

  f32x4 acc[4][4] = {};

  // lds-DMA lane mapping: LDS byte (q*4096 + tid*16) -> row = q*64 + tid/4, k-group = tid&3
  const int dm = tid >> 2, dkg = tid & 3;

  auto mfma_block = [&]() {
#pragma unroll
    for (int h = 0; h < 2; ++h) {
      short8 af[4], bfv[4];
#pragma unroll
      for (int mt = 0; mt < 4; ++mt)
        af[mt] = *(const short8*)&As[h * HSA + (wm + mt * 16 + lrow) * PA + lkg * 8];
#pragma unroll
      for (int nt = 0; nt < 4; ++nt)
        bfv[nt] = *(const short8*)&Bs[h * 4096 + (wn + nt * 16 + lrow) * 32 + lkg * 8];
#pragma unroll
      for (int mt = 0; mt < 4; ++mt)
#pragma unroll
        for (int nt = 0; nt < 4; ++nt)
          acc[mt][nt] = __builtin_amdgcn_mfma_f32_16x16x32_bf16(af[mt], bfv[nt], acc[mt][nt], 0, 0, 0);
    }
  };
  auto stage_b = [&](int k0) {
#pragma unroll
    for (int h = 0; h < 2; ++h)
#pragma unroll
      for (int q = 0; q < 2; ++q) {
        const unsigned short* src = B + (size_t)(n0 + q * 64 + dm) * p.ldb + (k0 + h * 32 + dkg * 8);
        __builtin_amdgcn_global_load_lds((gas_t*)src,
                                         (las_t*)&Bs[h * 4096 + q * 2048 + wid * 512],
                                         16, 0, 0);
      }
  };

  const int nIter = p.K >> 6;
  const int nIter1 = p.kSplit ? (p.kSplit >> 6) : nIter;

  for (int it = 0; it < nIter1; ++it) {
    const int k0 = it << 6;
    if (TA == 0) {
#pragma unroll
      for (int h = 0; h < 2; ++h)
#pragma unroll
        for (int q = 0; q < 2; ++q) {
          const unsigned short* src = A + (size_t)(m0 + q * 64 + dm) * p.lda + (k0 + h * 32 + dkg * 8);
          __builtin_amdgcn_global_load_lds((gas_t*)src,
                                           (las_t*)&As[h * HSA + q * 2048 + wid * 512],
                                           16, 0, 0);
        }
    } else {
      const int kk = tid & 31, mg = (tid >> 5) << 4;
#pragma unroll
      for (int h = 0; h < 2; ++h) {
        const unsigned short* src = A + (size_t)(k0 + h * 32 + kk) * p.lda + (m0 + mg);
        uint4 v0 = *(const uint4*)src;
        uint4 v1 = *(const uint4*)(src + 8);
        unsigned short tmp[16];
        *(uint4*)&tmp[0] = v0;
        *(uint4*)&tmp[8] = v1;
#pragma unroll
        for (int j = 0; j < 16; ++j) As[h * HSA + (mg + j) * PA + kk] = tmp[j];
      }
    }
    stage_b(k0);
    __syncthreads();
    mfma_block();
    __syncthreads();
  }

  // phase 2 (TA=0 only in practice): A from f32 source with in-register convert
  if (TA == 0 && p.kSplit) {
    for (int it = nIter1; it < nIter; ++it) {
      const int k0 = it << 6;
#pragma unroll
      for (int h = 0; h < 2; ++h) {
        const int ko = k0 + h * 32 - p.kSplit;
#pragma unroll
        for (int q = 0; q < 2; ++q) {
          const float* src = A2f + (size_t)(m0 + q * 64 + dm) * p.lda2 + (ko + dkg * 8);
          float4 v0 = *(const float4*)src;
          float4 v1 = *(const float4*)(src + 4);
          __attribute__((aligned(16))) unsigned short t[8];
          t[0] = f2bf(v0.x); t[1] = f2bf(v0.y); t[2] = f2bf(v0.z); t[3] = f2bf(v0.w);
          t[4] = f2bf(v1.x); t[5] = f2bf(v1.y); t[6] = f2bf(v1.z); t[7] = f2bf(v1.w);
          *(uint4*)&As[h * HSA + (q * 64 + dm) * 32 + dkg * 8] = *(const uint4*)t;
        }
      }
      stage_b(k0);
      __syncthreads();
      mfma_block();
      __syncthreads();
    }
  }

  unsigned short* Cu = (unsigned short*)Cvp + (size_t)zb * p.sCb + (size_t)zh * p.sCh;
  float* Cf = (float*)Cvp + (size_t)zb * p.sCb + (size_t)zh * p.sCh;

  // hoisted epilogue operands (16 row values, 4 col values)
  float mp[16], ms[4];
  if constexpr (EPI == 1) {
#pragma unroll
    for (int mt = 0; mt < 4; ++mt)
#pragma unroll
      for (int r = 0; r < 4; ++r)
        mp[mt * 4 + r] = p.mask_p[(size_t)zb * p.M + (m0 + wm + mt * 16 + lkg * 4 + r)];
#pragma unroll
    for (int nt = 0; nt < 4; ++nt)
      ms[nt] = p.mask_s[(size_t)zb * p.N + (n0 + wn + nt * 16 + lrow)];
  }
  if constexpr (EPI == 3) {
#pragma unroll
    for (int nt = 0; nt < 4; ++nt)
      ms[nt] = bias[n0 + wn + nt * 16 + lrow];
  }

#pragma unroll
  for (int mt = 0; mt < 4; ++mt) {
#pragma unroll
    for (int nt = 0; nt < 4; ++nt) {
      f32x4 a = acc[mt][nt];
#pragma unroll
      for (int r = 0; r < 4; ++r) {
        const int grow = m0 + wm + mt * 16 + lkg * 4 + r;  // C/D: row=(lane>>4)*4+reg
        const int gcol = n0 + wn + nt * 16 + lrow;         //      col=lane&15
        const size_t idx = (size_t)grow * p.ldc + gcol;
        const float v = a[r];
        if constexpr (EPI == 0) {
          Cu[idx] = f2bf(v);
        } else if constexpr (EPI == 1) {
          Cu[idx] = f2bf(fast_tanh(v) * (mp[mt * 4 + r] * ms[nt]));
        } else if constexpr (EPI == 2) {
          // relu output >= 0, pool initialized to 0 -> int compare == float compare
          atomicMax((int*)Cf + idx, __float_as_int(fmaxf(v, 0.f)));
        } else {
          Cf[idx] = fmaxf(v + ms[nt], 0.f);
        }
      }
    }
  }
}

template <int TA, int EPI>
__global__ __launch_bounds__(256) void gemm_k(GemmP p) {
  extern __shared__ char smem[];
  gemm_body<TA, EPI>(p, blockIdx.x, blockIdx.y, blockIdx.z, smem);
}

// two independent GEMM problems in one dispatch (flat grid, per-block decode)
template <int TA1, int EPI1, int TA2, int EPI2>
__global__ __launch_bounds__(256) void gemm_pair_k(GemmP a, GemmP b, int nA) {
  extern __shared__ char smem[];
  int bid = blockIdx.x;
  if (bid < nA) {
    const int per = a.nbx * a.nby;
    const int z = bid / per, r = bid % per;
    gemm_body<TA1, EPI1>(a, r % a.nbx, r / a.nbx, z, smem);
  } else {
    bid -= nA;
    const int per = b.nbx * b.nby;
    const int z = bid / per, r = bid % per;
    gemm_body<TA2, EPI2>(b, r % b.nbx, r / b.nbx, z, smem);
  }
}

// ---- fused preamble: input cvt, 4 weight transposes, pool zeroing ----
__device__ __forceinline__ void trans_body(const float* src, unsigned short* dst,
                                           int R, int C, int bx, int by, float (*tile)[33]) {
  const int r0 = by * 32, c0 = bx * 32;
  const int tx = threadIdx.x & 31, ty = threadIdx.x >> 5;  // 32 x 8
#pragma unroll
  for (int j = 0; j < 4; ++j)
    tile[ty + j * 8][tx] = src[(size_t)(r0 + ty + j * 8) * C + (c0 + tx)];
  __syncthreads();
#pragma unroll
  for (int j = 0; j < 4; ++j)
    dst[(size_t)(c0 + ty + j * 8) * R + (r0 + tx)] = f2bf(tile[tx][ty + j * 8]);
}

// block ranges: [0,8192) cvt P,S; [8192,10240) WaT; [10240,11264) WpT/WsT;
// [11264,11904) WfpT/WfsT; [11904,13952) zero pools
__global__ __launch_bounds__(256) void prep_k(const float* P, const float* S,
                                              unsigned short* Pbf, unsigned short* Sbf,
                                              const float* W_aff, unsigned short* WaT,
                                              const float* W_p, unsigned short* WpT,
                                              const float* W_s, unsigned short* WsT,
                                              const float* W_fp, unsigned short* WfpT,
                                              const float* W_fs, unsigned short* WfsT,
                                              float* poolz) {
  __shared__ float tile[32][33];
  const int bid = blockIdx.x;
  if (bid < 8192) {
    const int n4 = 1048576;  // 16*512*512/4
    int i = bid * 256 + threadIdx.x;
    const float4* s = (const float4*)P;
    ushort4* d = (ushort4*)Pbf;
    if (i >= n4) { i -= n4; s = (const float4*)S; d = (ushort4*)Sbf; }
    float4 v = s[i];
    ushort4 o;
    o.x = f2bf(v.x); o.y = f2bf(v.y); o.z = f2bf(v.z); o.w = f2bf(v.w);
    d[i] = o;
  } else if (bid < 10240) {
    const int l = bid - 8192;                      // 16x16 tiles x 8 heads
    const int z = l >> 8, r = l & 255;
    trans_body(W_aff + (size_t)z * 262144, WaT + (size_t)z * 262144, 512, 512,
               r & 15, r >> 4, tile);
  } else if (bid < 11264) {
    const int l = bid - 10240;                     // 32x16 tiles x 2
    const int z = l >> 9, r = l & 511;
    trans_body(z ? W_s : W_p, z ? WsT : WpT, 512, 1024, r & 31, r >> 5, tile);
  } else if (bid < 11904) {
    const int l = bid - 11264;                     // 16x20 tiles x 2
    const int z = l / 320, r = l % 320;
    trans_body(z ? W_fs : W_fp, z ? WfsT : WfpT, 640, 512, r & 15, r >> 4, tile);
  } else {
    const int i = (bid - 11904) * 256 + threadIdx.x;  // 524288 float4s = 8.4 MB
    ((float4*)poolz)[i] = float4{0.f, 0.f, 0.f, 0.f};
  }
}

extern "C" void kernel_launch(void* const* d_in, const int* in_sizes, int n_in,
                              void* d_out, int out_size, void* d_ws, size_t ws_size,
                              hipStream_t stream) {
  (void)in_sizes; (void)n_in; (void)out_size; (void)ws_size;
  const float* primary   = (const float*)d_in[0];
  const float* secondary = (const float*)d_in[1];
  const float* pmask     = (const float*)d_in[2];
  const float* smask     = (const float*)d_in[3];
  const float* W_aff     = (const float*)d_in[4];
  const float* W_p       = (const float*)d_in[5];
  const float* W_s       = (const float*)d_in[6];
  const float* W_fp      = (const float*)d_in[7];
  const float* b_fp      = (const float*)d_in[8];
  const float* W_fs      = (const float*)d_in[9];
  const float* b_fs      = (const float*)d_in[10];

  constexpr int Bb = 16, L = 512, Dd = 512, Hh = 8, HDd = 128, INNER = 1024, CAT = 640;
  constexpr int NT = Hh * Dd;                      // 4096
  constexpr long long LD = (long long)L * Dd;      // 262144
  constexpr long long LL = (long long)L * L;       // 262144

  char* base = (char*)d_ws;
  size_t off = 0;
  auto alloc = [&](size_t bytes) -> void* {
    void* r = base + off;
    off += (bytes + 255) & ~(size_t)255;
    return r;
  };

  unsigned short* Pbf   = (unsigned short*)alloc((size_t)Bb * L * Dd * 2);
  unsigned short* Sbf   = (unsigned short*)alloc((size_t)Bb * L * Dd * 2);
  unsigned short* WaT   = (unsigned short*)alloc((size_t)NT * Dd * 2);        // [h*512+f][e]
  unsigned short* WpT   = (unsigned short*)alloc((size_t)INNER * Dd * 2);     // [n][e]
  unsigned short* WsT   = (unsigned short*)alloc((size_t)INNER * Dd * 2);
  unsigned short* WfpT  = (unsigned short*)alloc((size_t)Dd * CAT * 2);       // [n][k]
  unsigned short* WfsT  = (unsigned short*)alloc((size_t)Dd * CAT * 2);
  unsigned short* psT   = (unsigned short*)alloc((size_t)Bb * INNER * L * 2); // [b][d][j]
  unsigned short* ppT   = (unsigned short*)alloc((size_t)Bb * INNER * L * 2); // [b][d][i]
  unsigned short* Tbuf  = (unsigned short*)alloc((size_t)Bb * L * NT * 2);    // [b*L+i][h*512+f]
  unsigned short* affb  = (unsigned short*)alloc((size_t)Bb * Hh * L * L * 2);
  float* pool_p = (float*)alloc((size_t)Bb * L * HDd * 4);                    // adjacent with pool_s
  float* pool_s = (float*)alloc((size_t)Bb * L * HDd * 4);

  // ---- 1) fused preamble ----
  prep_k<<<dim3(13952), dim3(256), 0, stream>>>(primary, secondary, Pbf, Sbf,
                                                W_aff, WaT, W_p, WpT, W_s, WsT,
                                                W_fp, WfpT, W_fs, WfsT, pool_p);

  // ---- 2) Tbuf = P @ Waff(stacked)  ||  psT/ppT = (S@W_s)^T / (P@W_p)^T ----
  {
    GemmP a{};
    a.A = Pbf; a.lda = Dd;
    a.Bm = WaT; a.ldb = Dd;
    a.C = Tbuf; a.ldc = NT;
    a.M = Bb * L; a.N = NT; a.K = Dd; a.Hh = 1; a.nbx = 64; a.nby = 32;

    GemmP b{};
    b.A = WsT; b.lda = Dd; b.sAb = 0;
    b.Bm = Sbf; b.ldb = Dd; b.sBb = LD;
    b.C = psT; b.ldc = L; b.sCb = (long long)INNER * L;
    b.A_b = WpT; b.Bm_b = Pbf; b.C_b = ppT;
    b.M = INNER; b.N = L; b.K = Dd; b.Hh = 1; b.zSplit = Bb; b.nbx = 8; b.nby = 4;

    gemm_pair_k<0, 0, 0, 0><<<dim3(2048 + 1024), dim3(256), 32768, stream>>>(a, b, 2048);
  }

  // ---- 3) aff[b,h] = tanh(T[b,h] @ S_b^T) * mask ----
  {
    GemmP g{};
    g.A = Tbuf; g.lda = NT; g.sAb = (long long)L * NT; g.sAh = Dd;
    g.Bm = Sbf; g.ldb = Dd; g.sBb = LD; g.sBh = 0;
    g.C = affb; g.ldc = L; g.sCb = (long long)Hh * LL; g.sCh = LL;
    g.mask_p = pmask; g.mask_s = smask;
    g.M = L; g.N = L; g.K = Dd; g.Hh = Hh;
    gemm_k<0, 1><<<dim3(4, 4, Bb * Hh), dim3(256), 32768, stream>>>(g);
  }

  // ---- 4) pool_s (fast A)  ||  pool_p (A = affb as K x M) ----
  {
    GemmP g4{};
    g4.A = affb; g4.lda = L; g4.sAb = (long long)Hh * LL; g4.sAh = LL;
    g4.Bm = psT; g4.ldb = L; g4.sBb = (long long)INNER * L; g4.sBh = (long long)HDd * L;
    g4.C = pool_s; g4.ldc = HDd; g4.sCb = (long long)L * HDd; g4.sCh = 0;
    g4.M = L; g4.N = HDd; g4.K = L; g4.Hh = Hh; g4.nbx = 4; g4.nby = 1;

    GemmP g5 = g4;
    g5.Bm = ppT;
    g5.C = pool_p;

    gemm_pair_k<0, 2, 1, 2><<<dim3(512 + 512), dim3(256), 36864, stream>>>(g4, g5, 512);
  }

  // ---- 5) merged output FFNs; A2 = f32 pools converted during staging ----
  {
    GemmP g{};
    g.A = Pbf; g.lda = Dd;
    g.A2f = pool_s; g.lda2 = HDd; g.kSplit = Dd;
    g.Bm = WfpT; g.ldb = CAT;
    g.C = d_out; g.ldc = Dd;
    g.bias = b_fp;
    g.A_b = Sbf; g.A2f_b = pool_p; g.Bm_b = WfsT;
    g.C_b = (float*)d_out + (size_t)Bb * L * Dd;
    g.bias_b = b_fs;
    g.M = Bb * L; g.N = Dd; g.K = CAT; g.Hh = 1; g.zSplit = 1;
    gemm_k<0, 3><<<dim3(64, 4, 2), dim3(256), 32768, stream>>>(g);
  }
}

// Round 9
// 333.360 us; speedup vs baseline: 1.0831x; 1.0345x over previous
//
#include <hip/hip_runtime.h>
#include <hip/hip_bf16.h>

typedef short short8 __attribute__((ext_vector_type(8)));
typedef float f32x16 __attribute__((ext_vector_type(16)));

#define BM 128
#define BN 128

typedef const __attribute__((address_space(1))) void gas_t;
typedef __attribute__((address_space(3))) void las_t;

__device__ __forceinline__ unsigned short f2bf(float f) {
  unsigned int u = __float_as_uint(f);
  u += 0x7FFFu + ((u >> 16) & 1u);   // round-to-nearest-even
  return (unsigned short)(u >> 16);
}

// tanh via single v_exp_f32 + v_rcp_f32: tanh(x) = 1 - 2/(e^2x + 1).
__device__ __forceinline__ float fast_tanh(float x) {
  x = fminf(fmaxf(x, -10.f), 10.f);
  float t = __builtin_amdgcn_exp2f(x * 2.8853900817779268f);  // 2*log2(e)
  return 1.f - 2.f * __builtin_amdgcn_rcpf(t + 1.f);
}

struct GemmP {
  const unsigned short* A;
  const unsigned short* Bm;
  void* C;
  const float* A2f;            // f32 second A source for k >= kSplit (converted during staging)
  // alt pointer set for merged launches: used when z >= zSplit
  const unsigned short* A_b;
  const unsigned short* Bm_b;
  void* C_b;
  const float* A2f_b;
  const float* mask_p;
  const float* mask_s;
  const float* bias;
  const float* bias_b;
  long long sAb, sAh, sBb, sBh, sCb, sCh;
  int lda, lda2, ldb, ldc, M, N, K, Hh, kSplit, zSplit, nbx, nby;
};

// TA: 0 = A is M x K row-major (lds-DMA staging, pitch 32); 1 = A stored K x M (VALU transpose staging, pitch 40).
// B always N x K row-major (lds-DMA).
// EPI: 0 bf16 store; 1 tanh*mask bf16; 2 relu+atomicMax f32 pool; 3 +bias,relu f32.
// MFMA: 32x32x16 (2382-2495 TF ubench vs 2075 for 16x16x32; half the instruction count).
// Wave tile 64x64 = 2x2 of 32x32. A/B frag: [m=lane&31][k=(lane>>5)*8+j].
// C/D: col=lane&31, row=(reg&3)+8*(reg>>2)+4*(lane>>5)  [m74/m101 verified].
template <int TA, int EPI>
__device__ __forceinline__ void gemm_body(const GemmP& p, int bx, int by, int bz, char* smem_) {
  constexpr int PA = (TA == 0) ? 32 : 40;
  constexpr int HSA = (TA == 0) ? 4096 : 5120;  // shorts per A half-tile
  unsigned short* As = (unsigned short*)smem_;
  unsigned short* Bs = (unsigned short*)(smem_ + 2 * HSA * 2);

  int z = bz;
  const unsigned short* Abase = p.A;
  const unsigned short* Bbase = p.Bm;
  void* Cvp = p.C;
  const float* A2f = p.A2f;
  const float* bias = p.bias;
  if (p.zSplit && z >= p.zSplit) {
    z -= p.zSplit;
    Abase = p.A_b; Bbase = p.Bm_b; Cvp = p.C_b; A2f = p.A2f_b; bias = p.bias_b;
  }
  const int zb = z / p.Hh, zh = z % p.Hh;
  const unsigned short* A = Abase + (size_t)zb * p.sAb + (size_t)zh * p.sAh;
  const unsigned short* B = Bbase + (size_t)zb * p.sBb + (size_t)zh * p.sBh;
  const int m0 = bx * BM, n0 = by * BN;
  const int tid = threadIdx.x;
  const int wid = tid >> 6, lane = tid & 63;
  const int wm = (wid >> 1) * 64, wn = (wid & 1) * 64;
  const int lrow = lane & 31;          // row within 32x32 frag
  const int lk8 = (lane >> 5) * 8;     // k-offset within 16-k chunk

  f32x16 acc[2][2] = {};

  // lds-DMA lane mapping: LDS byte (q*4096 + tid*16) -> row = q*64 + tid/4, k-group = tid&3
  const int dm = tid >> 2, dkg = tid & 3;

  auto mfma_block = [&]() {
#pragma unroll
    for (int h = 0; h < 2; ++h)
#pragma unroll
      for (int kc = 0; kc < 2; ++kc) {
        short8 af[2], bfv[2];
#pragma unroll
        for (int mt = 0; mt < 2; ++mt)
          af[mt] = *(const short8*)&As[h * HSA + (wm + mt * 32 + lrow) * PA + kc * 16 + lk8];
#pragma unroll
        for (int nt = 0; nt < 2; ++nt)
          bfv[nt] = *(const short8*)&Bs[h * 4096 + (wn + nt * 32 + lrow) * 32 + kc * 16 + lk8];
#pragma unroll
        for (int mt = 0; mt < 2; ++mt)
#pragma unroll
          for (int nt = 0; nt < 2; ++nt)
            acc[mt][nt] = __builtin_amdgcn_mfma_f32_32x32x16_bf16(af[mt], bfv[nt], acc[mt][nt], 0, 0, 0);
      }
  };
  auto stage_b = [&](int k0) {
#pragma unroll
    for (int h = 0; h < 2; ++h)
#pragma unroll
      for (int q = 0; q < 2; ++q) {
        const unsigned short* src = B + (size_t)(n0 + q * 64 + dm) * p.ldb + (k0 + h * 32 + dkg * 8);
        __builtin_amdgcn_global_load_lds((gas_t*)src,
                                         (las_t*)&Bs[h * 4096 + q * 2048 + wid * 512],
                                         16, 0, 0);
      }
  };

  const int nIter = p.K >> 6;
  const int nIter1 = p.kSplit ? (p.kSplit >> 6) : nIter;

  for (int it = 0; it < nIter1; ++it) {
    const int k0 = it << 6;
    if (TA == 0) {
#pragma unroll
      for (int h = 0; h < 2; ++h)
#pragma unroll
        for (int q = 0; q < 2; ++q) {
          const unsigned short* src = A + (size_t)(m0 + q * 64 + dm) * p.lda + (k0 + h * 32 + dkg * 8);
          __builtin_amdgcn_global_load_lds((gas_t*)src,
                                           (las_t*)&As[h * HSA + q * 2048 + wid * 512],
                                           16, 0, 0);
        }
    } else {
      const int kk = tid & 31, mg = (tid >> 5) << 4;
#pragma unroll
      for (int h = 0; h < 2; ++h) {
        const unsigned short* src = A + (size_t)(k0 + h * 32 + kk) * p.lda + (m0 + mg);
        uint4 v0 = *(const uint4*)src;
        uint4 v1 = *(const uint4*)(src + 8);
        unsigned short tmp[16];
        *(uint4*)&tmp[0] = v0;
        *(uint4*)&tmp[8] = v1;
#pragma unroll
        for (int j = 0; j < 16; ++j) As[h * HSA + (mg + j) * PA + kk] = tmp[j];
      }
    }
    stage_b(k0);
    __syncthreads();
    mfma_block();
    __syncthreads();
  }

  // phase 2 (TA=0 only in practice): A from f32 source with in-register convert
  if (TA == 0 && p.kSplit) {
    for (int it = nIter1; it < nIter; ++it) {
      const int k0 = it << 6;
#pragma unroll
      for (int h = 0; h < 2; ++h) {
        const int ko = k0 + h * 32 - p.kSplit;
#pragma unroll
        for (int q = 0; q < 2; ++q) {
          const float* src = A2f + (size_t)(m0 + q * 64 + dm) * p.lda2 + (ko + dkg * 8);
          float4 v0 = *(const float4*)src;
          float4 v1 = *(const float4*)(src + 4);
          __attribute__((aligned(16))) unsigned short t[8];
          t[0] = f2bf(v0.x); t[1] = f2bf(v0.y); t[2] = f2bf(v0.z); t[3] = f2bf(v0.w);
          t[4] = f2bf(v1.x); t[5] = f2bf(v1.y); t[6] = f2bf(v1.z); t[7] = f2bf(v1.w);
          *(uint4*)&As[h * HSA + (q * 64 + dm) * 32 + dkg * 8] = *(const uint4*)t;
        }
      }
      stage_b(k0);
      __syncthreads();
      mfma_block();
      __syncthreads();
    }
  }

  unsigned short* Cu = (unsigned short*)Cvp + (size_t)zb * p.sCb + (size_t)zh * p.sCh;
  float* Cf = (float*)Cvp + (size_t)zb * p.sCb + (size_t)zh * p.sCh;

  // C/D row within 32x32: rl(reg) = (reg&3) + 8*(reg>>2) + 4*(lane>>5); col = lane&31
  const int rbase = 4 * (lane >> 5);

  // hoisted epilogue operands
  float mp[2][16], ms[2];
  if constexpr (EPI == 1) {
#pragma unroll
    for (int mt = 0; mt < 2; ++mt)
#pragma unroll
      for (int reg = 0; reg < 16; ++reg) {
        const int rl = (reg & 3) + 8 * (reg >> 2) + rbase;
        mp[mt][reg] = p.mask_p[(size_t)zb * p.M + (m0 + wm + mt * 32 + rl)];
      }
#pragma unroll
    for (int nt = 0; nt < 2; ++nt)
      ms[nt] = p.mask_s[(size_t)zb * p.N + (n0 + wn + nt * 32 + lrow)];
  }
  if constexpr (EPI == 3) {
#pragma unroll
    for (int nt = 0; nt < 2; ++nt)
      ms[nt] = bias[n0 + wn + nt * 32 + lrow];
  }

#pragma unroll
  for (int mt = 0; mt < 2; ++mt) {
#pragma unroll
    for (int nt = 0; nt < 2; ++nt) {
      f32x16 a = acc[mt][nt];
#pragma unroll
      for (int reg = 0; reg < 16; ++reg) {
        const int rl = (reg & 3) + 8 * (reg >> 2) + rbase;
        const int grow = m0 + wm + mt * 32 + rl;
        const int gcol = n0 + wn + nt * 32 + lrow;
        const size_t idx = (size_t)grow * p.ldc + gcol;
        const float v = a[reg];
        if constexpr (EPI == 0) {
          Cu[idx] = f2bf(v);
        } else if constexpr (EPI == 1) {
          Cu[idx] = f2bf(fast_tanh(v) * (mp[mt][reg] * ms[nt]));
        } else if constexpr (EPI == 2) {
          // relu output >= 0, pool initialized to 0 -> int compare == float compare
          atomicMax((int*)Cf + idx, __float_as_int(fmaxf(v, 0.f)));
        } else {
          Cf[idx] = fmaxf(v + ms[nt], 0.f);
        }
      }
    }
  }
}

template <int TA, int EPI>
__global__ __launch_bounds__(256) void gemm_k(GemmP p) {
  extern __shared__ char smem[];
  gemm_body<TA, EPI>(p, blockIdx.x, blockIdx.y, blockIdx.z, smem);
}

// two independent GEMM problems in one dispatch (flat grid, per-block decode)
template <int TA1, int EPI1, int TA2, int EPI2>
__global__ __launch_bounds__(256) void gemm_pair_k(GemmP a, GemmP b, int nA) {
  extern __shared__ char smem[];
  int bid = blockIdx.x;
  if (bid < nA) {
    const int per = a.nbx * a.nby;
    const int z = bid / per, r = bid % per;
    gemm_body<TA1, EPI1>(a, r % a.nbx, r / a.nbx, z, smem);
  } else {
    bid -= nA;
    const int per = b.nbx * b.nby;
    const int z = bid / per, r = bid % per;
    gemm_body<TA2, EPI2>(b, r % b.nbx, r / b.nbx, z, smem);
  }
}

// ---- fused preamble: input cvt, 4 weight transposes, pool zeroing ----
__device__ __forceinline__ void trans_body(const float* src, unsigned short* dst,
                                           int R, int C, int bx, int by, float (*tile)[33]) {
  const int r0 = by * 32, c0 = bx * 32;
  const int tx = threadIdx.x & 31, ty = threadIdx.x >> 5;  // 32 x 8
#pragma unroll
  for (int j = 0; j < 4; ++j)
    tile[ty + j * 8][tx] = src[(size_t)(r0 + ty + j * 8) * C + (c0 + tx)];
  __syncthreads();
#pragma unroll
  for (int j = 0; j < 4; ++j)
    dst[(size_t)(c0 + ty + j * 8) * R + (r0 + tx)] = f2bf(tile[tx][ty + j * 8]);
}

// block ranges: [0,8192) cvt P,S; [8192,10240) WaT; [10240,11264) WpT/WsT;
// [11264,11904) WfpT/WfsT; [11904,13952) zero pools
__global__ __launch_bounds__(256) void prep_k(const float* P, const float* S,
                                              unsigned short* Pbf, unsigned short* Sbf,
                                              const float* W_aff, unsigned short* WaT,
                                              const float* W_p, unsigned short* WpT,
                                              const float* W_s, unsigned short* WsT,
                                              const float* W_fp, unsigned short* WfpT,
                                              const float* W_fs, unsigned short* WfsT,
                                              float* poolz) {
  __shared__ float tile[32][33];
  const int bid = blockIdx.x;
  if (bid < 8192) {
    const int n4 = 1048576;  // 16*512*512/4
    int i = bid * 256 + threadIdx.x;
    const float4* s = (const float4*)P;
    ushort4* d = (ushort4*)Pbf;
    if (i >= n4) { i -= n4; s = (const float4*)S; d = (ushort4*)Sbf; }
    float4 v = s[i];
    ushort4 o;
    o.x = f2bf(v.x); o.y = f2bf(v.y); o.z = f2bf(v.z); o.w = f2bf(v.w);
    d[i] = o;
  } else if (bid < 10240) {
    const int l = bid - 8192;                      // 16x16 tiles x 8 heads
    const int z = l >> 8, r = l & 255;
    trans_body(W_aff + (size_t)z * 262144, WaT + (size_t)z * 262144, 512, 512,
               r & 15, r >> 4, tile);
  } else if (bid < 11264) {
    const int l = bid - 10240;                     // 32x16 tiles x 2
    const int z = l >> 9, r = l & 511;
    trans_body(z ? W_s : W_p, z ? WsT : WpT, 512, 1024, r & 31, r >> 5, tile);
  } else if (bid < 11904) {
    const int l = bid - 11264;                     // 16x20 tiles x 2
    const int z = l / 320, r = l % 320;
    trans_body(z ? W_fs : W_fp, z ? WfsT : WfpT, 640, 512, r & 15, r >> 4, tile);
  } else {
    const int i = (bid - 11904) * 256 + threadIdx.x;  // 524288 float4s = 8.4 MB
    ((float4*)poolz)[i] = float4{0.f, 0.f, 0.f, 0.f};
  }
}

extern "C" void kernel_launch(void* const* d_in, const int* in_sizes, int n_in,
                              void* d_out, int out_size, void* d_ws, size_t ws_size,
                              hipStream_t stream) {
  (void)in_sizes; (void)n_in; (void)out_size; (void)ws_size;
  const float* primary   = (const float*)d_in[0];
  const float* secondary = (const float*)d_in[1];
  const float* pmask     = (const float*)d_in[2];
  const float* smask     = (const float*)d_in[3];
  const float* W_aff     = (const float*)d_in[4];
  const float* W_p       = (const float*)d_in[5];
  const float* W_s       = (const float*)d_in[6];
  const float* W_fp      = (const float*)d_in[7];
  const float* b_fp      = (const float*)d_in[8];
  const float* W_fs      = (const float*)d_in[9];
  const float* b_fs      = (const float*)d_in[10];

  constexpr int Bb = 16, L = 512, Dd = 512, Hh = 8, HDd = 128, INNER = 1024, CAT = 640;
  constexpr int NT = Hh * Dd;                      // 4096
  constexpr long long LD = (long long)L * Dd;      // 262144
  constexpr long long LL = (long long)L * L;       // 262144

  char* base = (char*)d_ws;
  size_t off = 0;
  auto alloc = [&](size_t bytes) -> void* {
    void* r = base + off;
    off += (bytes + 255) & ~(size_t)255;
    return r;
  };

  unsigned short* Pbf   = (unsigned short*)alloc((size_t)Bb * L * Dd * 2);
  unsigned short* Sbf   = (unsigned short*)alloc((size_t)Bb * L * Dd * 2);
  unsigned short* WaT   = (unsigned short*)alloc((size_t)NT * Dd * 2);        // [h*512+f][e]
  unsigned short* WpT   = (unsigned short*)alloc((size_t)INNER * Dd * 2);     // [n][e]
  unsigned short* WsT   = (unsigned short*)alloc((size_t)INNER * Dd * 2);
  unsigned short* WfpT  = (unsigned short*)alloc((size_t)Dd * CAT * 2);       // [n][k]
  unsigned short* WfsT  = (unsigned short*)alloc((size_t)Dd * CAT * 2);
  unsigned short* psT   = (unsigned short*)alloc((size_t)Bb * INNER * L * 2); // [b][d][j]
  unsigned short* ppT   = (unsigned short*)alloc((size_t)Bb * INNER * L * 2); // [b][d][i]
  unsigned short* Tbuf  = (unsigned short*)alloc((size_t)Bb * L * NT * 2);    // [b*L+i][h*512+f]
  unsigned short* affb  = (unsigned short*)alloc((size_t)Bb * Hh * L * L * 2);
  float* pool_p = (float*)alloc((size_t)Bb * L * HDd * 4);                    // adjacent with pool_s
  float* pool_s = (float*)alloc((size_t)Bb * L * HDd * 4);

  // ---- 1) fused preamble ----
  prep_k<<<dim3(13952), dim3(256), 0, stream>>>(primary, secondary, Pbf, Sbf,
                                                W_aff, WaT, W_p, WpT, W_s, WsT,
                                                W_fp, WfpT, W_fs, WfsT, pool_p);

  // ---- 2) Tbuf = P @ Waff(stacked)  ||  psT/ppT = (S@W_s)^T / (P@W_p)^T ----
  {
    GemmP a{};
    a.A = Pbf; a.lda = Dd;
    a.Bm = WaT; a.ldb = Dd;
    a.C = Tbuf; a.ldc = NT;
    a.M = Bb * L; a.N = NT; a.K = Dd; a.Hh = 1; a.nbx = 64; a.nby = 32;

    GemmP b{};
    b.A = WsT; b.lda = Dd; b.sAb = 0;
    b.Bm = Sbf; b.ldb = Dd; b.sBb = LD;
    b.C = psT; b.ldc = L; b.sCb = (long long)INNER * L;
    b.A_b = WpT; b.Bm_b = Pbf; b.C_b = ppT;
    b.M = INNER; b.N = L; b.K = Dd; b.Hh = 1; b.zSplit = Bb; b.nbx = 8; b.nby = 4;

    gemm_pair_k<0, 0, 0, 0><<<dim3(2048 + 1024), dim3(256), 32768, stream>>>(a, b, 2048);
  }

  // ---- 3) aff[b,h] = tanh(T[b,h] @ S_b^T) * mask ----
  {
    GemmP g{};
    g.A = Tbuf; g.lda = NT; g.sAb = (long long)L * NT; g.sAh = Dd;
    g.Bm = Sbf; g.ldb = Dd; g.sBb = LD; g.sBh = 0;
    g.C = affb; g.ldc = L; g.sCb = (long long)Hh * LL; g.sCh = LL;
    g.mask_p = pmask; g.mask_s = smask;
    g.M = L; g.N = L; g.K = Dd; g.Hh = Hh;
    gemm_k<0, 1><<<dim3(4, 4, Bb * Hh), dim3(256), 32768, stream>>>(g);
  }

  // ---- 4) pool_s (fast A)  ||  pool_p (A = affb as K x M) ----
  {
    GemmP g4{};
    g4.A = affb; g4.lda = L; g4.sAb = (long long)Hh * LL; g4.sAh = LL;
    g4.Bm = psT; g4.ldb = L; g4.sBb = (long long)INNER * L; g4.sBh = (long long)HDd * L;
    g4.C = pool_s; g4.ldc = HDd; g4.sCb = (long long)L * HDd; g4.sCh = 0;
    g4.M = L; g4.N = HDd; g4.K = L; g4.Hh = Hh; g4.nbx = 4; g4.nby = 1;

    GemmP g5 = g4;
    g5.Bm = ppT;
    g5.C = pool_p;

    gemm_pair_k<0, 2, 1, 2><<<dim3(512 + 512), dim3(256), 36864, stream>>>(g4, g5, 512);
  }

  // ---- 5) merged output FFNs; A2 = f32 pools converted during staging ----
  {
    GemmP g{};
    g.A = Pbf; g.lda = Dd;
    g.A2f = pool_s; g.lda2 = HDd; g.kSplit = Dd;
    g.Bm = WfpT; g.ldb = CAT;
    g.C = d_out; g.ldc = Dd;
    g.bias = b_fp;
    g.A_b = Sbf; g.A2f_b = pool_p; g.Bm_b = WfsT;
    g.C_b = (float*)d_out + (size_t)Bb * L * Dd;
    g.bias_b = b_fs;
    g.M = Bb * L; g.N = Dd; g.K = CAT; g.Hh = 1; g.zSplit = 1;
    gemm_k<0, 3><<<dim3(64, 4, 2), dim3(256), 32768, stream>>>(g);
  }
}